// Round 2
// 314.451 us; speedup vs baseline: 1.1090x; 1.1090x over previous
//
#include <hip/hip_runtime.h>

// SpatialRNN3D: out[...,d*64+c] = x + r_d, where r is a 1st-order IIR along the
// scan direction: r_j = relu(w*x_prev) + max(w,0)*r_prev. |w| < 0.05 so the
// state decays by 0.05^s — an 8-element halo reconstructs it to ~1e-11.
//
// V2 (resubmit after infra failure; code unchanged): direction-PAIR fusion.
// One wave loads a 64-px chunk of a line into registers ONCE and runs both the
// forward (right/down) and backward (left/up) scans over it, writing both
// output quarters (adjacent 256B blocks -> 512B contiguous per pixel).
// Read amplification: (64 + 2*8*(7/8))/64 ~= 1.22x per pair vs 1.47x per
// single dir before => reads ~376MB -> ~156MB.
// Non-temporal stores keep x resident in L2/LLC across passes.
//
// 2 pairs * 512 lines * 8 chunks = 8192 waves = 2048 blocks of 256.

#define HH 512
#define WW 512
#define CC 64
#define CHUNK 64
#define HALO 8
#define NCH (WW / CHUNK)   // 8 chunks per line

__global__ __launch_bounds__(256) void spatial_rnn_kernel(
    const float* __restrict__ x,
    const float* __restrict__ kr,
    const float* __restrict__ kl,
    const float* __restrict__ kd,
    const float* __restrict__ ku,
    float* __restrict__ out)
{
    const int tid  = threadIdx.x;
    const int c    = tid & 63;                  // channel = lane
    const int wv   = blockIdx.x * 4 + (tid >> 6);   // 0..8191

    const int pair = wv >> 12;   // 0: horizontal (right+left), 1: vertical (down+up)
    const int rem  = wv & 4095;

    float wA, wB;                // A = forward dir (right/down), B = backward (left/up)
    int ix0, dxi, oA0, oB0, dout, chunk;
    if (pair == 0) {
        const int line = rem >> 3;              // row; block's 4 waves = 4 chunks of it
        chunk = rem & 7;
        const int p0 = chunk * CHUNK;
        wA = kr[c];                             // k_right[0,0,c,0]
        wB = kl[2 * CC + c];                    // k_left[0,2,c,0]
        ix0  = line * (WW * CC) + p0 * CC + c;  dxi = CC;
        oA0  = line * (WW * 4 * CC) + p0 * (4 * CC) + c;   // quarter [0:64]
        oB0  = oA0 + CC;                                   // quarter [64:128]
        dout = 4 * CC;
    } else {
        const int line = rem & 511;             // column; block's 4 waves = 4 ADJACENT
        chunk = rem >> 9;                       //   columns -> 1KB contiguous per row
        const int p0 = chunk * CHUNK;
        wA = kd[c];                             // k_down[0,0,c,0]
        wB = ku[2 * CC + c];                    // k_up[2,0,c,0]
        ix0  = p0 * (WW * CC) + line * CC + c;  dxi = WW * CC;
        oA0  = p0 * (WW * 4 * CC) + line * (4 * CC) + 2 * CC + c;  // quarter [128:192]
        oB0  = oA0 + CC;                                           // quarter [192:256]
        dout = WW * 4 * CC;
    }
    const float wpA = fmaxf(wA, 0.0f);
    const float wpB = fmaxf(wB, 0.0f);

    // Load the chunk into registers once; both scans consume it.
    float xv[CHUNK];
    #pragma unroll
    for (int t = 0; t < CHUNK; ++t)
        xv[t] = x[(long)ix0 + (long)t * dxi];

    // Forward warm-up: process j = p0-8 .. p0-1 ascending.
    float rA = 0.0f;
    if (chunk != 0) {
        float hv[HALO];
        #pragma unroll
        for (int t = 0; t < HALO; ++t)
            hv[t] = x[(long)ix0 - (long)(HALO - t) * dxi];
        #pragma unroll
        for (int t = 0; t < HALO; ++t)
            rA = fmaxf(wA * hv[t], 0.0f) + wpA * rA;
    }

    // Backward warm-up: process j = p0+71 .. p0+64 descending.
    float rB = 0.0f;
    if (chunk != NCH - 1) {
        float hv[HALO];
        #pragma unroll
        for (int t = 0; t < HALO; ++t)
            hv[t] = x[(long)ix0 + (long)(CHUNK + HALO - 1 - t) * dxi];
        #pragma unroll
        for (int t = 0; t < HALO; ++t)
            rB = fmaxf(wB * hv[t], 0.0f) + wpB * rB;
    }

    // Forward scan (out[j] = x[j] + rA_{j-1}), ascending.
    #pragma unroll
    for (int t = 0; t < CHUNK; ++t) {
        __builtin_nontemporal_store(xv[t] + rA, &out[(long)oA0 + (long)t * dout]);
        rA = fmaxf(wA * xv[t], 0.0f) + wpA * rA;
    }
    // Backward scan (out[j] = x[j] + rB_{j+1}), descending.
    #pragma unroll
    for (int t = CHUNK - 1; t >= 0; --t) {
        __builtin_nontemporal_store(xv[t] + rB, &out[(long)oB0 + (long)t * dout]);
        rB = fmaxf(wB * xv[t], 0.0f) + wpB * rB;
    }
}

extern "C" void kernel_launch(void* const* d_in, const int* in_sizes, int n_in,
                              void* d_out, int out_size, void* d_ws, size_t ws_size,
                              hipStream_t stream) {
    const float* x  = (const float*)d_in[0];
    const float* kr = (const float*)d_in[1];
    const float* kl = (const float*)d_in[2];
    const float* kd = (const float*)d_in[3];
    const float* ku = (const float*)d_in[4];
    float* out = (float*)d_out;

    // 2 pairs * 512 lines * 8 chunks = 8192 waves -> 2048 blocks of 256
    spatial_rnn_kernel<<<2048, 256, 0, stream>>>(x, kr, kl, kd, ku, out);
}